// Round 9
// baseline (484.521 us; speedup 1.0000x reference)
//
#include <hip/hip_runtime.h>

// Geometry (from reference): B=4, C=8, D=48, H=128, W=160
#define HW    20480      // H*W
#define DHW   983040     // D*H*W (channel stride, floats)
#define CDHW  7864320    // C*D*H*W (batch stride, floats)
#define NPIX  81920      // B*H*W
#define SLAB  1024       // pixels per block task
#define NSLAB 20         // HW / SLAB
#define DSTEP 8          // d-slices per block task
#define NCHNK 6          // 48 / DSTEP
#define NBLK  (4 * NSLAB * NCHNK)   // 480 blocks
#define EPS   1e-5f

// 16B-per-lane async global->LDS (dest = wave-uniform base + lane*16).
static __device__ __forceinline__ void gload_lds16(const float* g, float* l) {
    __builtin_amdgcn_global_load_lds(
        (const __attribute__((address_space(1))) unsigned int*)g,
        (__attribute__((address_space(3))) unsigned int*)l,
        16, 0, 0);
}

// Single compute kernel: each block = (batch, 1024-px slab, 8-slice d-chunk).
// Folded weights computed per-block (inputs tiny, L2-resident).
// Partial d-max written to ws[chunk][pixel] with plain stores (no atomics).
__global__ __launch_bounds__(512, 4)
void mlp_kernel(const float* __restrict__ x,
                const float* __restrict__ w0, const float* __restrict__ g0,
                const float* __restrict__ b0, const float* __restrict__ m0,
                const float* __restrict__ v0,
                const float* __restrict__ w1, const float* __restrict__ g1,
                const float* __restrict__ b1, const float* __restrict__ m1,
                const float* __restrict__ v1,
                const float* __restrict__ w2,
                float* __restrict__ ws)
{
    // LDS: double-buffered x slabs (64 KB) + folded f32 weights (~1.2 KB).
    __shared__ __align__(16) float lx[2][8][SLAB];
    __shared__ __align__(16) float lw0[128];   // [o][c] o<16 c<8
    __shared__ float lb0[16];
    __shared__ __align__(16) float lw1[128];   // [j][o] j<8 o<16
    __shared__ float lb1[8];
    __shared__ __align__(16) float lw2[8];

    const int tid  = threadIdx.x;
    const int lane = tid & 63;
    const int wv   = tid >> 6;          // 0..7; wave stages channel wv each step

    // Task decode: 480 = 4 batches x 20 slabs x 6 chunks.
    const int t     = blockIdx.x;
    const int batch = t / (NSLAB * NCHNK);
    const int r     = t - batch * (NSLAB * NCHNK);
    const int slab  = r / NCHNK;
    const int chunk = r - slab * NCHNK;
    const float* xb = x + (size_t)batch * CDHW + (size_t)(chunk * DSTEP) * HW + slab * SLAB;

    // ---- per-block BN fold into LDS (all wave-uniform broadcast reads later) ----
    if (tid < 128) {
        int o = tid >> 3;
        lw0[tid] = w0[tid] * (g0[o] * rsqrtf(v0[o] + EPS));
    } else if (tid < 256) {
        int k = tid - 128, j = k >> 4;
        lw1[k] = w1[k] * (g1[j] * rsqrtf(v1[j] + EPS));
    } else if (tid < 272) {
        int o = tid - 256;
        lb0[o] = b0[o] - m0[o] * g0[o] * rsqrtf(v0[o] + EPS);
    } else if (tid < 280) {
        int j = tid - 272;
        lb1[j] = b1[j] - m1[j] * g1[j] * rsqrtf(v1[j] + EPS);
    } else if (tid < 288) {
        lw2[tid - 280] = w2[tid - 280];
    }

    // Stage slice dd: wave wv streams channel wv (4 KB = 4 x 1KB instrs).
#define STAGE(buf, dd)                                                           \
    {                                                                            \
        const float* _s = xb + (size_t)(dd) * HW + (size_t)wv * DHW + lane * 4;  \
        float* _d = &lx[buf][wv][0];                                             \
        _Pragma("unroll")                                                        \
        for (int i = 0; i < 4; ++i) gload_lds16(_s + i * 256, _d + i * 256);     \
    }

    STAGE(0, 0)
    __syncthreads();   // weights folded + slice 0 staged

    float maxv0 = -1e30f, maxv1 = -1e30f;

#pragma unroll
    for (int dd = 0; dd < DSTEP; ++dd) {
        const int buf = dd & 1;
        if (dd + 1 < DSTEP) STAGE(buf ^ 1, dd + 1)

        // this thread's 2 px x 8 ch from LDS (ds_read_b64, 2-way = free)
        float xr[8][2];
#pragma unroll
        for (int c = 0; c < 8; ++c) {
            float2 v = *(const float2*)&lx[buf][c][tid * 2];
            xr[c][0] = v.x; xr[c][1] = v.y;
        }

        // layer 0: 8 -> 16, relu
        float h0[16][2];
#pragma unroll
        for (int o = 0; o < 16; ++o) {
            float4 wA = *(const float4*)&lw0[o * 8];
            float4 wB = *(const float4*)&lw0[o * 8 + 4];
            float  bA = lb0[o];
#pragma unroll
            for (int px = 0; px < 2; ++px) {
                float a = bA;
                a = fmaf(wA.x, xr[0][px], a); a = fmaf(wA.y, xr[1][px], a);
                a = fmaf(wA.z, xr[2][px], a); a = fmaf(wA.w, xr[3][px], a);
                a = fmaf(wB.x, xr[4][px], a); a = fmaf(wB.y, xr[5][px], a);
                a = fmaf(wB.z, xr[6][px], a); a = fmaf(wB.w, xr[7][px], a);
                h0[o][px] = fmaxf(a, 0.0f);
            }
        }

        // layer 1: 16 -> 8, relu
        float h1[8][2];
#pragma unroll
        for (int j = 0; j < 8; ++j) {
            float4 u0 = *(const float4*)&lw1[j * 16];
            float4 u1 = *(const float4*)&lw1[j * 16 + 4];
            float4 u2 = *(const float4*)&lw1[j * 16 + 8];
            float4 u3 = *(const float4*)&lw1[j * 16 + 12];
            float  bj = lb1[j];
#pragma unroll
            for (int px = 0; px < 2; ++px) {
                float a = bj;
                a = fmaf(u0.x, h0[0][px], a);  a = fmaf(u0.y, h0[1][px], a);
                a = fmaf(u0.z, h0[2][px], a);  a = fmaf(u0.w, h0[3][px], a);
                a = fmaf(u1.x, h0[4][px], a);  a = fmaf(u1.y, h0[5][px], a);
                a = fmaf(u1.z, h0[6][px], a);  a = fmaf(u1.w, h0[7][px], a);
                a = fmaf(u2.x, h0[8][px], a);  a = fmaf(u2.y, h0[9][px], a);
                a = fmaf(u2.z, h0[10][px], a); a = fmaf(u2.w, h0[11][px], a);
                a = fmaf(u3.x, h0[12][px], a); a = fmaf(u3.y, h0[13][px], a);
                a = fmaf(u3.z, h0[14][px], a); a = fmaf(u3.w, h0[15][px], a);
                h1[j][px] = fmaxf(a, 0.0f);
            }
        }

        // layer 2: 8 -> 1 (bias2 deferred to finish), running max
        {
            float4 wA = *(const float4*)&lw2[0];
            float4 wB = *(const float4*)&lw2[4];
            float a0 = 0.f, a1 = 0.f;
            a0 = fmaf(wA.x, h1[0][0], a0); a0 = fmaf(wA.y, h1[1][0], a0);
            a0 = fmaf(wA.z, h1[2][0], a0); a0 = fmaf(wA.w, h1[3][0], a0);
            a0 = fmaf(wB.x, h1[4][0], a0); a0 = fmaf(wB.y, h1[5][0], a0);
            a0 = fmaf(wB.z, h1[6][0], a0); a0 = fmaf(wB.w, h1[7][0], a0);
            a1 = fmaf(wA.x, h1[0][1], a1); a1 = fmaf(wA.y, h1[1][1], a1);
            a1 = fmaf(wA.z, h1[2][1], a1); a1 = fmaf(wA.w, h1[3][1], a1);
            a1 = fmaf(wB.x, h1[4][1], a1); a1 = fmaf(wB.y, h1[5][1], a1);
            a1 = fmaf(wB.z, h1[6][1], a1); a1 = fmaf(wB.w, h1[7][1], a1);
            maxv0 = fmaxf(maxv0, a0);
            maxv1 = fmaxf(maxv1, a1);
        }

        __syncthreads();   // staged next buffer complete; current reusable
    }
#undef STAGE

    // Plain store of this chunk's partial max (no init needed, no atomics).
    float2 st; st.x = maxv0; st.y = maxv1;
    *(float2*)&ws[(size_t)chunk * NPIX + (size_t)batch * HW + slab * SLAB + tid * 2] = st;
}

// Reduce 6 chunk-partials, add bias2, sigmoid (monotone => commutes with max).
__global__ __launch_bounds__(256)
void finish_kernel(const float* __restrict__ ws, const float* __restrict__ bias2,
                   float* __restrict__ out)
{
    int i = blockIdx.x * 256 + threadIdx.x;
    float m = ws[i];
#pragma unroll
    for (int c = 1; c < NCHNK; ++c) m = fmaxf(m, ws[(size_t)c * NPIX + i]);
    m += bias2[0];
    out[i] = 1.0f / (1.0f + __expf(-m));
}

extern "C" void kernel_launch(void* const* d_in, const int* in_sizes, int n_in,
                              void* d_out, int out_size, void* d_ws, size_t ws_size,
                              hipStream_t stream) {
    const float* x1 = (const float*)d_in[0];
    float* ws = (float*)d_ws;   // needs 6 * 81920 * 4 = 2 MB

    mlp_kernel<<<NBLK, 512, 0, stream>>>(
        x1,
        (const float*)d_in[1], (const float*)d_in[2], (const float*)d_in[3],
        (const float*)d_in[4], (const float*)d_in[5],
        (const float*)d_in[6], (const float*)d_in[7], (const float*)d_in[8],
        (const float*)d_in[9], (const float*)d_in[10],
        (const float*)d_in[11],
        ws);
    finish_kernel<<<NPIX / 256, 256, 0, stream>>>(ws, (const float*)d_in[12],
                                                  (float*)d_out);
}

// Round 10
// 44.632 us; speedup vs baseline: 10.8558x; 10.8558x over previous
//
#include <hip/hip_runtime.h>

// Geometry (from reference): B=4, C=8, D=48, H=128, W=160
#define HW    20480      // H*W
#define DHW   983040     // D*H*W (channel stride, floats)
#define CDHW  7864320    // C*D*H*W (batch stride, floats)
#define NPIX  81920      // B*H*W
#define SLAB  1024       // pixels per block task
#define NSLAB 20         // HW / SLAB
#define DSTEP 8          // d-slices per block task
#define NCHNK 6          // 48 / DSTEP
#define NBLK  (4 * NSLAB * NCHNK)   // 480 blocks
#define EPS   1e-5f

// 16B-per-lane async global->LDS (dest = wave-uniform base + lane*16).
static __device__ __forceinline__ void gload_lds16(const float* g, float* l) {
    __builtin_amdgcn_global_load_lds(
        (const __attribute__((address_space(1))) unsigned int*)g,
        (__attribute__((address_space(3))) unsigned int*)l,
        16, 0, 0);
}

// Each block = (batch, 1024-px slab, 8-slice d-chunk). Weights folded
// per-block (tiny, L2-resident). Partial d-max -> ws[chunk][pixel], plain stores.
__global__ __launch_bounds__(256, 2)
void mlp_kernel(const float* __restrict__ x,
                const float* __restrict__ w0, const float* __restrict__ g0,
                const float* __restrict__ b0, const float* __restrict__ m0,
                const float* __restrict__ v0,
                const float* __restrict__ w1, const float* __restrict__ g1,
                const float* __restrict__ b1, const float* __restrict__ m1,
                const float* __restrict__ v1,
                const float* __restrict__ w2,
                float* __restrict__ ws)
{
    // LDS: double-buffered x slabs (64 KB) + folded f32 weights (~1.2 KB).
    __shared__ __align__(16) float lx[2][8][SLAB];
    __shared__ __align__(16) float lw0[128];   // [o][c] o<16 c<8
    __shared__ float lb0[16];
    __shared__ __align__(16) float lw1[128];   // [j][o] j<8 o<16
    __shared__ float lb1[8];
    __shared__ __align__(16) float lw2[8];

    const int tid  = threadIdx.x;
    const int lane = tid & 63;
    const int wv   = tid >> 6;          // 0..3; wave stages channels 2wv, 2wv+1

    // Task decode: 480 = 4 batches x 20 slabs x 6 chunks.
    const int t     = blockIdx.x;
    const int batch = t / (NSLAB * NCHNK);
    const int r     = t - batch * (NSLAB * NCHNK);
    const int slab  = r / NCHNK;
    const int chunk = r - slab * NCHNK;
    const float* xb = x + (size_t)batch * CDHW + (size_t)(chunk * DSTEP) * HW + slab * SLAB;

    // ---- per-block BN fold into LDS ----
    if (tid < 128) {
        int o = tid >> 3;
        lw0[tid] = w0[tid] * (g0[o] * rsqrtf(v0[o] + EPS));
    } else {
        int k = tid - 128, j = k >> 4;
        lw1[k] = w1[k] * (g1[j] * rsqrtf(v1[j] + EPS));
    }
    if (tid < 16) lb0[tid] = b0[tid] - m0[tid] * g0[tid] * rsqrtf(v0[tid] + EPS);
    if (tid >= 32 && tid < 40) {
        int j = tid - 32;
        lb1[j] = b1[j] - m1[j] * g1[j] * rsqrtf(v1[j] + EPS);
    }
    if (tid >= 48 && tid < 56) lw2[tid - 48] = w2[tid - 48];

    // Stage slice dd: wave wv streams channels 2wv,2wv+1 (4 KB each).
#define STAGE(buf, dd)                                                            \
    {                                                                             \
        const float* _s0 = xb + (size_t)(dd) * HW + (size_t)(2 * wv) * DHW + lane * 4; \
        const float* _s1 = _s0 + DHW;                                             \
        float* _d0 = &lx[buf][2 * wv][0];                                         \
        float* _d1 = &lx[buf][2 * wv + 1][0];                                     \
        _Pragma("unroll")                                                         \
        for (int i = 0; i < 4; ++i) gload_lds16(_s0 + i * 256, _d0 + i * 256);    \
        _Pragma("unroll")                                                         \
        for (int i = 0; i < 4; ++i) gload_lds16(_s1 + i * 256, _d1 + i * 256);    \
    }

    STAGE(0, 0)
    __syncthreads();   // weights folded + slice 0 staged

    float maxv[4];
#pragma unroll
    for (int k = 0; k < 4; ++k) maxv[k] = -1e30f;

    for (int dd = 0; dd < DSTEP; ++dd) {
        const int buf = dd & 1;
        if (dd + 1 < DSTEP) STAGE(buf ^ 1, dd + 1)

        // ---- this thread's 4 px x 8 ch from LDS ----
        float xr[8][4];
#pragma unroll
        for (int c = 0; c < 8; ++c) {
            float4 v = *(const float4*)&lx[buf][c][tid * 4];
            xr[c][0] = v.x; xr[c][1] = v.y; xr[c][2] = v.z; xr[c][3] = v.w;
        }

        // ---- layer 0: 8 -> 16, relu ----
        float h0[16][4];
#pragma unroll
        for (int o = 0; o < 16; ++o) {
            float4 wA = *(const float4*)&lw0[o * 8];
            float4 wB = *(const float4*)&lw0[o * 8 + 4];
            float  bA = lb0[o];
#pragma unroll
            for (int px = 0; px < 4; ++px) {
                float a = bA;
                a = fmaf(wA.x, xr[0][px], a); a = fmaf(wA.y, xr[1][px], a);
                a = fmaf(wA.z, xr[2][px], a); a = fmaf(wA.w, xr[3][px], a);
                a = fmaf(wB.x, xr[4][px], a); a = fmaf(wB.y, xr[5][px], a);
                a = fmaf(wB.z, xr[6][px], a); a = fmaf(wB.w, xr[7][px], a);
                h0[o][px] = fmaxf(a, 0.0f);
            }
        }

        // ---- layer 1: 16 -> 8, relu ----
        float h1[8][4];
#pragma unroll
        for (int j = 0; j < 8; ++j) {
            float4 u0 = *(const float4*)&lw1[j * 16];
            float4 u1 = *(const float4*)&lw1[j * 16 + 4];
            float4 u2 = *(const float4*)&lw1[j * 16 + 8];
            float4 u3 = *(const float4*)&lw1[j * 16 + 12];
            float  bj = lb1[j];
#pragma unroll
            for (int px = 0; px < 4; ++px) {
                float a = bj;
                a = fmaf(u0.x, h0[0][px], a);  a = fmaf(u0.y, h0[1][px], a);
                a = fmaf(u0.z, h0[2][px], a);  a = fmaf(u0.w, h0[3][px], a);
                a = fmaf(u1.x, h0[4][px], a);  a = fmaf(u1.y, h0[5][px], a);
                a = fmaf(u1.z, h0[6][px], a);  a = fmaf(u1.w, h0[7][px], a);
                a = fmaf(u2.x, h0[8][px], a);  a = fmaf(u2.y, h0[9][px], a);
                a = fmaf(u2.z, h0[10][px], a); a = fmaf(u2.w, h0[11][px], a);
                a = fmaf(u3.x, h0[12][px], a); a = fmaf(u3.y, h0[13][px], a);
                a = fmaf(u3.z, h0[14][px], a); a = fmaf(u3.w, h0[15][px], a);
                h1[j][px] = fmaxf(a, 0.0f);
            }
        }

        // ---- layer 2: 8 -> 1 (bias2 deferred), running max ----
        {
            float4 wA = *(const float4*)&lw2[0];
            float4 wB = *(const float4*)&lw2[4];
#pragma unroll
            for (int px = 0; px < 4; ++px) {
                float a = 0.0f;
                a = fmaf(wA.x, h1[0][px], a); a = fmaf(wA.y, h1[1][px], a);
                a = fmaf(wA.z, h1[2][px], a); a = fmaf(wA.w, h1[3][px], a);
                a = fmaf(wB.x, h1[4][px], a); a = fmaf(wB.y, h1[5][px], a);
                a = fmaf(wB.z, h1[6][px], a); a = fmaf(wB.w, h1[7][px], a);
                maxv[px] = fmaxf(maxv[px], a);
            }
        }

        __syncthreads();   // staged buffer ready; current buffer reusable
    }
#undef STAGE

    // Plain store of this chunk's partial max (no init, no atomics).
    float4 st; st.x = maxv[0]; st.y = maxv[1]; st.z = maxv[2]; st.w = maxv[3];
    *(float4*)&ws[(size_t)chunk * NPIX + (size_t)batch * HW + slab * SLAB + tid * 4] = st;
}

// Reduce 6 chunk-partials, add bias2, sigmoid (monotone => commutes with max).
__global__ __launch_bounds__(256)
void finish_kernel(const float* __restrict__ ws, const float* __restrict__ bias2,
                   float* __restrict__ out)
{
    int i = blockIdx.x * 256 + threadIdx.x;
    float m = ws[i];
#pragma unroll
    for (int c = 1; c < NCHNK; ++c) m = fmaxf(m, ws[(size_t)c * NPIX + i]);
    m += bias2[0];
    out[i] = 1.0f / (1.0f + __expf(-m));
}

extern "C" void kernel_launch(void* const* d_in, const int* in_sizes, int n_in,
                              void* d_out, int out_size, void* d_ws, size_t ws_size,
                              hipStream_t stream) {
    const float* x1 = (const float*)d_in[0];
    float* ws = (float*)d_ws;   // needs 6 * 81920 * 4 = 2 MB

    mlp_kernel<<<NBLK, 256, 0, stream>>>(
        x1,
        (const float*)d_in[1], (const float*)d_in[2], (const float*)d_in[3],
        (const float*)d_in[4], (const float*)d_in[5],
        (const float*)d_in[6], (const float*)d_in[7], (const float*)d_in[8],
        (const float*)d_in[9], (const float*)d_in[10],
        (const float*)d_in[11],
        ws);
    finish_kernel<<<NPIX / 256, 256, 0, stream>>>(ws, (const float*)d_in[12],
                                                  (float*)d_out);
}

// Round 11
// 39.777 us; speedup vs baseline: 12.1810x; 1.1221x over previous
//
#include <hip/hip_runtime.h>

// Geometry (from reference): B=4, C=8, D=48, H=128, W=160
#define HW    20480      // H*W
#define DHW   983040     // D*H*W (channel stride, floats)
#define CDHW  7864320    // C*D*H*W (batch stride, floats)
#define NPIX  81920      // B*H*W
#define SLAB  1024       // pixels per block task
#define NSLAB 20         // HW / SLAB
#define DSTEP 8          // d-slices per block task
#define NCHNK 6          // 48 / DSTEP
#define NBLK  (4 * NSLAB * NCHNK)   // 480 blocks
#define EPS   1e-5f

typedef _Float16 half2v __attribute__((ext_vector_type(2)));

static __device__ __forceinline__ float dot2u(half2v a, unsigned wb, float c) {
#if __has_builtin(__builtin_amdgcn_fdot2)
    return __builtin_amdgcn_fdot2(a, __builtin_bit_cast(half2v, wb), c, false);
#else
    half2v b = __builtin_bit_cast(half2v, wb);
    return fmaf((float)a.x, (float)b.x, fmaf((float)a.y, (float)b.y, c));
#endif
}
static __device__ __forceinline__ half2v pk(float a, float b) {
#if __has_builtin(__builtin_amdgcn_cvt_pkrtz)
    return __builtin_bit_cast(half2v, __builtin_amdgcn_cvt_pkrtz(a, b));
#else
    half2v h; h.x = (_Float16)a; h.y = (_Float16)b; return h;
#endif
}
static __device__ __forceinline__ unsigned pku(float a, float b) {
    return __builtin_bit_cast(unsigned, pk(a, b));
}

// 16B-per-lane async global->LDS (dest = wave-uniform base + lane*16).
static __device__ __forceinline__ void gload_lds16(const float* g, float* l) {
    __builtin_amdgcn_global_load_lds(
        (const __attribute__((address_space(1))) unsigned int*)g,
        (__attribute__((address_space(3))) unsigned int*)l,
        16, 0, 0);
}

// Each block = (batch, 1024-px slab, 8-slice d-chunk); 512 thr, 2 px/thread.
// Weights folded per-block into LDS as f16 pairs; compute via v_dot2_f32_f16.
// Partial d-max -> ws[chunk][pixel], plain stores.
__global__ __launch_bounds__(512, 2)
void mlp_kernel(const float* __restrict__ x,
                const float* __restrict__ w0, const float* __restrict__ g0,
                const float* __restrict__ b0, const float* __restrict__ m0,
                const float* __restrict__ v0,
                const float* __restrict__ w1, const float* __restrict__ g1,
                const float* __restrict__ b1, const float* __restrict__ m1,
                const float* __restrict__ v1,
                const float* __restrict__ w2,
                float* __restrict__ ws)
{
    // LDS: double-buffered x slabs (64 KB) + f16-packed folded weights (~0.7 KB).
    __shared__ __align__(16) float    lx[2][8][SLAB];
    __shared__ __align__(16) unsigned lw0u[64];   // [o][i] o<16 i<4 (ch pairs)
    __shared__ __align__(16) float    lb0[16];
    __shared__ __align__(16) unsigned lw1u[64];   // [j][i] j<8 i<8 (h0 pairs)
    __shared__ __align__(16) float    lb1[8];
    __shared__ __align__(16) unsigned lw2u[4];

    const int tid  = threadIdx.x;
    const int lane = tid & 63;
    const int wv   = tid >> 6;          // 0..7; wave wv stages channel wv

    // Task decode: 480 = 4 batches x 20 slabs x 6 chunks.
    const int t     = blockIdx.x;
    const int batch = t / (NSLAB * NCHNK);
    const int r     = t - batch * (NSLAB * NCHNK);
    const int slab  = r / NCHNK;
    const int chunk = r - slab * NCHNK;
    const float* xb = x + (size_t)batch * CDHW + (size_t)(chunk * DSTEP) * HW + slab * SLAB;

    // ---- per-block BN fold into LDS (f16 pairs) ----
    if (tid < 16) {
        float sc = g0[tid] * rsqrtf(v0[tid] + EPS);
#pragma unroll
        for (int i = 0; i < 4; ++i)
            lw0u[tid * 4 + i] = pku(w0[tid * 8 + 2 * i] * sc, w0[tid * 8 + 2 * i + 1] * sc);
        lb0[tid] = b0[tid] - m0[tid] * sc;
    } else if (tid < 24) {
        int j = tid - 16;
        float sc = g1[j] * rsqrtf(v1[j] + EPS);
#pragma unroll
        for (int i = 0; i < 8; ++i)
            lw1u[j * 8 + i] = pku(w1[j * 16 + 2 * i] * sc, w1[j * 16 + 2 * i + 1] * sc);
        lb1[j] = b1[j] - m1[j] * sc;
    } else if (tid == 24) {
#pragma unroll
        for (int i = 0; i < 4; ++i) lw2u[i] = pku(w2[2 * i], w2[2 * i + 1]);
    }

    // Stage slice dd: wave wv streams channel wv (4 KB = 4 x 1KB instrs).
#define STAGE(buf, dd)                                                           \
    {                                                                            \
        const float* _s = xb + (size_t)(dd) * HW + (size_t)wv * DHW + lane * 4;  \
        float* _d = &lx[buf][wv][0];                                             \
        _Pragma("unroll")                                                        \
        for (int i = 0; i < 4; ++i) gload_lds16(_s + i * 256, _d + i * 256);     \
    }

    STAGE(0, 0)
    __syncthreads();   // weights folded + slice 0 staged

    float maxv0 = -1e30f, maxv1 = -1e30f;

    for (int dd = 0; dd < DSTEP; ++dd) {
        const int buf = dd & 1;
        if (dd + 1 < DSTEP) STAGE(buf ^ 1, dd + 1)

        // ---- this thread's 2 px x 8 ch from LDS, pack to f16 pairs ----
        half2v xh0[4], xh1[4];
#pragma unroll
        for (int i = 0; i < 4; ++i) {
            float2 va = *(const float2*)&lx[buf][2 * i][tid * 2];
            float2 vb = *(const float2*)&lx[buf][2 * i + 1][tid * 2];
            xh0[i] = pk(va.x, vb.x);
            xh1[i] = pk(va.y, vb.y);
        }

        // bias vectors (4 b128 + 2 b128, components picked statically)
        float4 b0v0 = *(const float4*)&lb0[0];
        float4 b0v1 = *(const float4*)&lb0[4];
        float4 b0v2 = *(const float4*)&lb0[8];
        float4 b0v3 = *(const float4*)&lb0[12];
        float4 b1v0 = *(const float4*)&lb1[0];
        float4 b1v1 = *(const float4*)&lb1[4];

        // ---- layer 0: 8 -> 16, relu, pack pairs ----
        unsigned hh0[8], hh1[8];   // packed h0 pairs per px
#pragma unroll
        for (int op = 0; op < 8; ++op) {
            uint4 wA = *(const uint4*)&lw0u[(2 * op) * 4];
            uint4 wB = *(const uint4*)&lw0u[(2 * op + 1) * 4];
            const float4& bq = (op < 2) ? ((op & 1) ? b0v0 : b0v0)
                                        : ((op & 1) ? b0v0 : b0v0); // placeholder (below)
            (void)bq;
            float bA, bB;
            switch (op) {   // compile-time resolved under unroll
                case 0: bA = b0v0.x; bB = b0v0.y; break;
                case 1: bA = b0v0.z; bB = b0v0.w; break;
                case 2: bA = b0v1.x; bB = b0v1.y; break;
                case 3: bA = b0v1.z; bB = b0v1.w; break;
                case 4: bA = b0v2.x; bB = b0v2.y; break;
                case 5: bA = b0v2.z; bB = b0v2.w; break;
                case 6: bA = b0v3.x; bB = b0v3.y; break;
                default: bA = b0v3.z; bB = b0v3.w; break;
            }
            float a0 = bA, b0a = bB, a1 = bA, b1a = bB;
            a0  = dot2u(xh0[0], wA.x, a0);  a0  = dot2u(xh0[1], wA.y, a0);
            a0  = dot2u(xh0[2], wA.z, a0);  a0  = dot2u(xh0[3], wA.w, a0);
            b0a = dot2u(xh0[0], wB.x, b0a); b0a = dot2u(xh0[1], wB.y, b0a);
            b0a = dot2u(xh0[2], wB.z, b0a); b0a = dot2u(xh0[3], wB.w, b0a);
            a1  = dot2u(xh1[0], wA.x, a1);  a1  = dot2u(xh1[1], wA.y, a1);
            a1  = dot2u(xh1[2], wA.z, a1);  a1  = dot2u(xh1[3], wA.w, a1);
            b1a = dot2u(xh1[0], wB.x, b1a); b1a = dot2u(xh1[1], wB.y, b1a);
            b1a = dot2u(xh1[2], wB.z, b1a); b1a = dot2u(xh1[3], wB.w, b1a);
            hh0[op] = pku(fmaxf(a0, 0.f), fmaxf(b0a, 0.f));
            hh1[op] = pku(fmaxf(a1, 0.f), fmaxf(b1a, 0.f));
        }

        // ---- layer 1: 16 -> 8, relu, pack pairs ----
        unsigned hq0[4], hq1[4];
#pragma unroll
        for (int jp = 0; jp < 4; ++jp) {
            uint4 wA0 = *(const uint4*)&lw1u[(2 * jp) * 8];
            uint4 wA1 = *(const uint4*)&lw1u[(2 * jp) * 8 + 4];
            uint4 wB0 = *(const uint4*)&lw1u[(2 * jp + 1) * 8];
            uint4 wB1 = *(const uint4*)&lw1u[(2 * jp + 1) * 8 + 4];
            float bA, bB;
            switch (jp) {
                case 0: bA = b1v0.x; bB = b1v0.y; break;
                case 1: bA = b1v0.z; bB = b1v0.w; break;
                case 2: bA = b1v1.x; bB = b1v1.y; break;
                default: bA = b1v1.z; bB = b1v1.w; break;
            }
#pragma unroll
            for (int px = 0; px < 2; ++px) {
                const unsigned* hh = px ? hh1 : hh0;
                float a = bA, b = bB;
                a = dot2u(__builtin_bit_cast(half2v, hh[0]), wA0.x, a);
                a = dot2u(__builtin_bit_cast(half2v, hh[1]), wA0.y, a);
                a = dot2u(__builtin_bit_cast(half2v, hh[2]), wA0.z, a);
                a = dot2u(__builtin_bit_cast(half2v, hh[3]), wA0.w, a);
                a = dot2u(__builtin_bit_cast(half2v, hh[4]), wA1.x, a);
                a = dot2u(__builtin_bit_cast(half2v, hh[5]), wA1.y, a);
                a = dot2u(__builtin_bit_cast(half2v, hh[6]), wA1.z, a);
                a = dot2u(__builtin_bit_cast(half2v, hh[7]), wA1.w, a);
                b = dot2u(__builtin_bit_cast(half2v, hh[0]), wB0.x, b);
                b = dot2u(__builtin_bit_cast(half2v, hh[1]), wB0.y, b);
                b = dot2u(__builtin_bit_cast(half2v, hh[2]), wB0.z, b);
                b = dot2u(__builtin_bit_cast(half2v, hh[3]), wB0.w, b);
                b = dot2u(__builtin_bit_cast(half2v, hh[4]), wB1.x, b);
                b = dot2u(__builtin_bit_cast(half2v, hh[5]), wB1.y, b);
                b = dot2u(__builtin_bit_cast(half2v, hh[6]), wB1.z, b);
                b = dot2u(__builtin_bit_cast(half2v, hh[7]), wB1.w, b);
                unsigned pv = pku(fmaxf(a, 0.f), fmaxf(b, 0.f));
                if (px) hq1[jp] = pv; else hq0[jp] = pv;
            }
        }

        // ---- layer 2: 8 -> 1 (bias2 deferred), running max ----
        {
            uint4 w2v = *(const uint4*)&lw2u[0];
            float a0 = 0.f, a1 = 0.f;
            a0 = dot2u(__builtin_bit_cast(half2v, hq0[0]), w2v.x, a0);
            a0 = dot2u(__builtin_bit_cast(half2v, hq0[1]), w2v.y, a0);
            a0 = dot2u(__builtin_bit_cast(half2v, hq0[2]), w2v.z, a0);
            a0 = dot2u(__builtin_bit_cast(half2v, hq0[3]), w2v.w, a0);
            a1 = dot2u(__builtin_bit_cast(half2v, hq1[0]), w2v.x, a1);
            a1 = dot2u(__builtin_bit_cast(half2v, hq1[1]), w2v.y, a1);
            a1 = dot2u(__builtin_bit_cast(half2v, hq1[2]), w2v.z, a1);
            a1 = dot2u(__builtin_bit_cast(half2v, hq1[3]), w2v.w, a1);
            maxv0 = fmaxf(maxv0, a0);
            maxv1 = fmaxf(maxv1, a1);
        }

        __syncthreads();   // staged buffer complete; current reusable
    }
#undef STAGE

    // Plain store of this chunk's partial max.
    float2 st; st.x = maxv0; st.y = maxv1;
    *(float2*)&ws[(size_t)chunk * NPIX + (size_t)batch * HW + slab * SLAB + tid * 2] = st;
}

// Reduce 6 chunk-partials, add bias2, sigmoid (monotone => commutes with max).
__global__ __launch_bounds__(256)
void finish_kernel(const float* __restrict__ ws, const float* __restrict__ bias2,
                   float* __restrict__ out)
{
    int i = blockIdx.x * 256 + threadIdx.x;
    float m = ws[i];
#pragma unroll
    for (int c = 1; c < NCHNK; ++c) m = fmaxf(m, ws[(size_t)c * NPIX + i]);
    m += bias2[0];
    out[i] = 1.0f / (1.0f + __expf(-m));
}

extern "C" void kernel_launch(void* const* d_in, const int* in_sizes, int n_in,
                              void* d_out, int out_size, void* d_ws, size_t ws_size,
                              hipStream_t stream) {
    const float* x1 = (const float*)d_in[0];
    float* ws = (float*)d_ws;   // needs 6 * 81920 * 4 = 2 MB

    mlp_kernel<<<NBLK, 512, 0, stream>>>(
        x1,
        (const float*)d_in[1], (const float*)d_in[2], (const float*)d_in[3],
        (const float*)d_in[4], (const float*)d_in[5],
        (const float*)d_in[6], (const float*)d_in[7], (const float*)d_in[8],
        (const float*)d_in[9], (const float*)d_in[10],
        (const float*)d_in[11],
        ws);
    finish_kernel<<<NPIX / 256, 256, 0, stream>>>(ws, (const float*)d_in[12],
                                                  (float*)d_out);
}